// Round 9
// baseline (255.969 us; speedup 1.0000x reference)
//
#include <hip/hip_runtime.h>

typedef _Float16 f16;
typedef f16 f16x8 __attribute__((ext_vector_type(8)));
typedef float f32x4 __attribute__((ext_vector_type(4)));
typedef float f32x16 __attribute__((ext_vector_type(16)));

#define BATCH   32768
#define NF      162
#define ACCH    1024
#define KSL     192
#define NKS2    12        // 32x32x16 K-steps per 192
#define NB      8
#define DIVQ    20
#define TM      32        // rows per tile (k_main)
#define NT      256       // k_main threads (4 waves)
#define NCH     128
#define NCHUNK  (ACCH/NCH) // 8
#define MAXTILE (BATCH/TM + NB)   // 1032

#define BINBLK  256
#define RPB     (BATCH / BINBLK)  // 128 rows per binning block

// workspace layout (bytes)
#define WS_WACC16   0
#define WS_W116     (WS_WACC16 + ACCH*KSL*2)        // 393216
#define WS_BUCKET   (WS_W116 + 256*2048*2)          // 1441792
#define WS_ORDER    (WS_BUCKET + BATCH*4)           // 1572864
#define WS_CNT      (WS_ORDER + BATCH*4)            // 1703936
#define WS_BASE     (WS_CNT + 64)
#define WS_PART     (WS_BASE + 64)                  // 256*8*4 = 8192
#define WS_BLKMAP   (WS_PART + BINBLK*NB*4)         // MAXTILE ints

// k_main dynamic LDS: Xb dbuf 2*32*128*2 = 16384 + psq 128
#define LDS_BYTES   16512

// ---------------- dispatch 1: fused prep + binning (R7 proven) ----------------
__global__ __launch_bounds__(512) void k_prepbin(const float* __restrict__ stm,
                                                 const float* __restrict__ Wacc,
                                                 const float* __restrict__ W1,
                                                 int* __restrict__ bucket,
                                                 int* __restrict__ part,
                                                 f16* __restrict__ waccF,
                                                 f16* __restrict__ w1F)
{
    if (blockIdx.x < BINBLK) {
        __shared__ int hist[NB];
        int tid = threadIdx.x;
        if (tid < NB) hist[tid] = 0;
        __syncthreads();
        int wv = tid >> 6, ln = tid & 63;
        int rowbase = blockIdx.x * RPB + wv * (RPB / 8);   // 16 rows per wave
        for (int i = 0; i < RPB / 8; i++) {
            int row = rowbase + i;
            const float* rp = stm + (long)row * NF;
            float s = 0.f;
            for (int k = ln; k < NF; k += 64) s += rp[k];
            for (int off = 32; off > 0; off >>= 1) s += __shfl_down(s, off);
            if (ln == 0) {
                int pc = (int)(s + 0.5f);
                int b = pc / DIVQ; if (b > NB - 1) b = NB - 1;
                bucket[row] = b;
                atomicAdd(&hist[b], 1);
            }
        }
        __syncthreads();
        if (tid < NB) part[blockIdx.x * NB + tid] = hist[tid];
    } else {
        int tid = (blockIdx.x - BINBLK) * blockDim.x + threadIdx.x;
        int stride = (gridDim.x - BINBLK) * blockDim.x;
        // waccF (32x32x16 B-frag): idx = (((c*12+ks)*2+kh)*128+n)*8+e, k=ks*16+kh*8+e
        for (int t = tid; t < ACCH * KSL; t += stride) {
            int e = t & 7, f = t >> 3;
            int n = f & 127, g = f >> 7;
            int kh = g & 1, h = g >> 1;
            int ks = h % NKS2, c = h / NKS2;
            int k = ks * 16 + kh * 8 + e;
            waccF[t] = (f16)((k < NF) ? Wacc[(c * 128 + n) * NF + k] : 0.f);
        }
        // w1F (16x16x32 B-frag): source-coalesced float4 reads
        for (int t4 = tid; t4 < 256 * 2048 / 4; t4 += stride) {
            int t = t4 * 4;
            float4 v = *(const float4*)(W1 + t);
            int n_g = t >> 11, k = t & 2047;
            int bkt = n_g >> 5, n = n_g & 31;
            int s = k >> 10, c = (k >> 7) & 7, ks = (k >> 5) & 3, l4b = (k >> 3) & 3;
            int e = k & 7;
            long basei = (((((long)(bkt * 2 + s) * 8 + c) * 16 + ks * 4 + l4b) * 32 + n) * 8) + e;
            w1F[basei + 0] = (f16)v.x;
            w1F[basei + 1] = (f16)v.y;
            w1F[basei + 2] = (f16)v.z;
            w1F[basei + 3] = (f16)v.w;
        }
    }
}

// ---------------- dispatch 2: self-prefix scatter + setup ----------------
// blocks [0,256): compute own per-bucket bases from part via wave scan, then scatter.
// block 256: compute cnt/base/blkmap for k_main.
__global__ __launch_bounds__(256) void k_scatter(const int* __restrict__ bucket,
                                                 const int* __restrict__ part,
                                                 int* __restrict__ order,
                                                 int* __restrict__ cnt,
                                                 int* __restrict__ base,
                                                 int* __restrict__ blkmap)
{
    __shared__ int tot[NB], bas[NB], pre[NB], lcur[NB];
    __shared__ int tstart[NB + 1];
    int tid = threadIdx.x, bid = blockIdx.x;
    int w = tid >> 6, ln = tid & 63;

    if (bid < BINBLK) {
        // per-bucket: total + exclusive prefix of part[0..bid) (4 blocks per lane)
        for (int b = w; b < NB; b += 4) {
            int j0 = ln * 4;
            int p0 = part[(j0 + 0) * NB + b];
            int p1 = part[(j0 + 1) * NB + b];
            int p2 = part[(j0 + 2) * NB + b];
            int p3 = part[(j0 + 3) * NB + b];
            int s4 = p0 + p1 + p2 + p3;
            int inc = s4;
            for (int off = 1; off < 64; off <<= 1) {
                int n = __shfl_up(inc, off);
                if (ln >= off) inc += n;
            }
            if (ln == 63) tot[b] = inc;
            int excg = inc - s4;              // exclusive prefix of 4-block granule ln
            int g = bid >> 2;
            int prr = __shfl(excg, g);
            int q0 = __shfl(p0, g), q1 = __shfl(p1, g), q2 = __shfl(p2, g);
            int r = bid & 3;
            if (r > 0) prr += q0;
            if (r > 1) prr += q1;
            if (r > 2) prr += q2;
            if (ln == 0) pre[b] = prr;
        }
        __syncthreads();
        if (tid == 0) {
            int a = 0;
            for (int q = 0; q < NB; q++) { bas[q] = a; a += tot[q]; }
            for (int q = 0; q < NB; q++) lcur[q] = bas[q] + pre[q];
        }
        __syncthreads();
        int blkstart = bid * RPB;
        for (int i = tid; i < RPB; i += 256) {
            int row = blkstart + i;
            int b = bucket[row];
            int pos = atomicAdd(&lcur[b], 1);
            order[pos] = row;
        }
    } else {
        // setup block: totals -> cnt/base/tstart/blkmap
        for (int b = w; b < NB; b += 4) {
            int j0 = ln * 4;
            int s4 = part[(j0 + 0) * NB + b] + part[(j0 + 1) * NB + b]
                   + part[(j0 + 2) * NB + b] + part[(j0 + 3) * NB + b];
            for (int off = 32; off > 0; off >>= 1) s4 += __shfl_down(s4, off);
            if (ln == 0) tot[b] = s4;
        }
        __syncthreads();
        if (tid == 0) {
            int a = 0, t = 0;
            for (int q = 0; q < NB; q++) {
                base[q] = a; cnt[q] = tot[q]; a += tot[q];
                tstart[q] = t; t += (tot[q] + TM - 1) / TM;
            }
            tstart[NB] = t;
        }
        __syncthreads();
        for (int i = tid; i < MAXTILE; i += 256) {
            int v = -1;
            for (int q = 0; q < NB; q++)
                if (i >= tstart[q] && i < tstart[q + 1]) v = q | ((i - tstart[q]) << 4);
            blkmap[i] = v;
        }
    }
}

// ---------------- dispatch 3: main fused NNUE (TM=32, 4 waves, 4 blocks/CU) ----------------
__global__ __launch_bounds__(NT, 4) void k_main(
    const float* __restrict__ stm, const float* __restrict__ nstm,
    const float* __restrict__ Wacc, const float* __restrict__ bacc,
    const float* __restrict__ b1, const float* __restrict__ W2,
    const float* __restrict__ b2, const float* __restrict__ W3,
    const float* __restrict__ b3,
    const f16* __restrict__ waccF, const f16* __restrict__ w1F,
    const int* __restrict__ cnt, const int* __restrict__ base,
    const int* __restrict__ order, const int* __restrict__ blkmap,
    float* __restrict__ out)
{
    int bm = blkmap[blockIdx.x];
    if (bm < 0) return;
    int bkt = bm & 15, tile = bm >> 4;
    int rowbase = base[bkt] + tile * TM;
    int nrows = cnt[bkt] - tile * TM; if (nrows > TM) nrows = TM;

    extern __shared__ __align__(16) char lds_raw[];
    f16* Xb  = (f16*)lds_raw;                           // [2][32][128] dbuf swizzled
    f16* h1s = (f16*)lds_raw;                           // [32][40] alias buf0
    f16* h2s = (f16*)(lds_raw + TM * 40 * 2);           // [32][40] alias buf0
    float* psq = (float*)(lds_raw + 2 * TM * NCH * 2);  // [32]

    int tid = threadIdx.x;
    int wv = tid >> 6, ln = tid & 63;
    int l15 = ln & 15, l4 = ln >> 4, l31 = ln & 31, kh = ln >> 5;
    int mt = wv >> 1, nh = wv & 1;
    int colc = wv * 32 + l31;                 // phase1 col within chunk

    int rowclamp = (l31 < nrows) ? l31 : (nrows - 1);
    int rowidx = order[rowbase + rowclamp];

    float bb1 = b1[bkt * 32 + nh * 16 + l15];
    f32x4 h1acc; h1acc[0] = h1acc[1] = h1acc[2] = h1acc[3] = bb1;

    const float* psqw = Wacc + (long)ACCH * NF;
    const f16x8* wfr  = (const f16x8*)waccF;
    const f16x8* w1fr = (const f16x8*)w1F;

    for (int s = 0; s < 2; s++) {
        const float* rp = (s ? nstm : stm) + (long)rowidx * NF;
        // ---- A-panel (12 x f16x8 per lane) direct from global; psqt on wave 0 only ----
        f16x8 af[NKS2];
        float pp = 0.f;
        #pragma unroll
        for (int ks = 0; ks < NKS2; ks++) {
            int k0 = ks * 16 + kh * 8;
            float v0=0.f,v1=0.f,v2=0.f,v3=0.f,v4=0.f,v5=0.f,v6=0.f,v7=0.f;
            if (k0 <= 152) {
                float2 a0 = *(const float2*)(rp + k0);
                float2 a1 = *(const float2*)(rp + k0 + 2);
                float2 a2 = *(const float2*)(rp + k0 + 4);
                float2 a3 = *(const float2*)(rp + k0 + 6);
                v0=a0.x; v1=a0.y; v2=a1.x; v3=a1.y;
                v4=a2.x; v5=a2.y; v6=a3.x; v7=a3.y;
                if (wv == 0) {
                    float4 pa = *(const float4*)(psqw + k0);
                    float4 pb = *(const float4*)(psqw + k0 + 4);
                    pp += v0*pa.x + v1*pa.y + v2*pa.z + v3*pa.w
                        + v4*pb.x + v5*pb.y + v6*pb.z + v7*pb.w;
                }
            } else if (k0 == 160) {
                float2 a0 = *(const float2*)(rp + 160);
                v0 = a0.x; v1 = a0.y;
                if (wv == 0) pp += v0*psqw[160] + v1*psqw[161];
            }
            f16x8 h;
            h[0]=(f16)v0; h[1]=(f16)v1; h[2]=(f16)v2; h[3]=(f16)v3;
            h[4]=(f16)v4; h[5]=(f16)v5; h[6]=(f16)v6; h[7]=(f16)v7;
            af[ks] = h;
        }
        if (wv == 0) {
            pp += __shfl_xor(pp, 32);
            if (kh == 0) {
                if (s) psq[l31] -= 0.5f * pp;
                else   psq[l31]  = 0.5f * pp;
            }
        }

        for (int c = 0; c < NCHUNK; c++) {
            // ---- phase 1: 32x32x16, A regs, B global (L2-hot) ----
            float bias = bacc[c * NCH + colc];
            f32x16 acc;
            #pragma unroll
            for (int q = 0; q < 16; q++) acc[q] = bias;
            const f16x8* wp = wfr + ((c * NKS2) * 2 + kh) * 128 + colc;
            #pragma unroll
            for (int ks = 0; ks < NKS2; ks++) {
                f16x8 bf = wp[ks * 256];
                acc = __builtin_amdgcn_mfma_f32_32x32x16_f16(af[ks], bf, acc, 0, 0, 0);
            }
            // epilogue: clip^2 -> Xb[(s*8+c)&1] (dbuf: 1 barrier per chunk)
            f16* xb = Xb + (((s << 3) | c) & 1) * TM * NCH;
            #pragma unroll
            for (int reg = 0; reg < 16; reg++) {
                int rr = 4 * kh + (reg & 3) + 8 * (reg >> 2);
                float v = acc[reg];
                v = fminf(fmaxf(v, 0.f), 1.f);
                v = v * v;
                xb[rr * NCH + ((((colc >> 3) ^ (rr & 7)) << 3) | (colc & 7))] = (f16)v;
            }
            __syncthreads();
            // ---- phase 2: h1 += act @ W1_chunk^T (16x16x32) ----
            const f16x8* w1p = w1fr + ((bkt * 2 + s) * 8 + c) * 512;
            #pragma unroll
            for (int ks = 0; ks < NCH / 32; ks++) {
                int s0 = ks * 4 + l4;
                int row = mt * 16 + l15;
                f16x8 a = *(const f16x8*)(xb + row * NCH + ((s0 ^ (row & 7)) << 3));
                f16x8 b = w1p[s0 * 32 + nh * 16 + l15];
                h1acc = __builtin_amdgcn_mfma_f32_16x16x32_f16(a, b, h1acc, 0, 0, 0);
            }
        }
    }
    __syncthreads();   // all phase2 reads done before h1s/h2s overwrite buf0

    // ---- h1 finalize ----
    #pragma unroll
    for (int jr = 0; jr < 4; jr++) {
        int row = mt * 16 + l4 * 4 + jr;
        int col = nh * 16 + l15;
        float v = fminf(fmaxf(h1acc[jr], 0.f), 1.f);
        h1s[row * 40 + col] = (f16)v;
    }
    __syncthreads();

    // ---- layer 3 ----
    {
        int nn = nh * 16 + l15;
        const float* w2r = W2 + (bkt * 32 + nn) * 32;
        float4 wa = *(const float4*)(w2r + l4 * 8);
        float4 wb = *(const float4*)(w2r + l4 * 8 + 4);
        f16x8 bfr;
        bfr[0]=(f16)wa.x; bfr[1]=(f16)wa.y; bfr[2]=(f16)wa.z; bfr[3]=(f16)wa.w;
        bfr[4]=(f16)wb.x; bfr[5]=(f16)wb.y; bfr[6]=(f16)wb.z; bfr[7]=(f16)wb.w;
        int row = mt * 16 + l15;
        f16x8 a = *(const f16x8*)(h1s + row * 40 + l4 * 8);
        float bb2 = b2[bkt * 32 + nn];
        f32x4 acc2; acc2[0] = acc2[1] = acc2[2] = acc2[3] = bb2;
        acc2 = __builtin_amdgcn_mfma_f32_16x16x32_f16(a, bfr, acc2, 0, 0, 0);
        #pragma unroll
        for (int jr = 0; jr < 4; jr++) {
            int r2 = mt * 16 + l4 * 4 + jr;
            float v = fminf(fmaxf(acc2[jr], 0.f), 1.f);
            h2s[r2 * 40 + nn] = (f16)v;
        }
    }
    __syncthreads();

    // ---- layer 4 + psqt ----
    if (tid < nrows) {
        const float* w3r = W3 + bkt * 32;
        float o = b3[bkt] + psq[tid];
        #pragma unroll 8
        for (int n = 0; n < 32; n++) o += (float)h2s[tid * 40 + n] * w3r[n];
        out[order[rowbase + tid]] = o;
    }
}

// ---------------- launcher ----------------
extern "C" void kernel_launch(void* const* d_in, const int* in_sizes, int n_in,
                              void* d_out, int out_size, void* d_ws, size_t ws_size,
                              hipStream_t stream)
{
    (void)in_sizes; (void)n_in; (void)out_size; (void)ws_size;
    const float* stm  = (const float*)d_in[0];
    const float* nstm = (const float*)d_in[1];
    const float* Wacc = (const float*)d_in[2];
    const float* bacc = (const float*)d_in[3];
    const float* W1   = (const float*)d_in[4];
    const float* b1   = (const float*)d_in[5];
    const float* W2   = (const float*)d_in[6];
    const float* b2   = (const float*)d_in[7];
    const float* W3   = (const float*)d_in[8];
    const float* b3   = (const float*)d_in[9];
    float* out = (float*)d_out;

    char* ws = (char*)d_ws;
    f16* waccF  = (f16*)(ws + WS_WACC16);
    f16* w1F    = (f16*)(ws + WS_W116);
    int* bucket = (int*)(ws + WS_BUCKET);
    int* order  = (int*)(ws + WS_ORDER);
    int* cnt    = (int*)(ws + WS_CNT);
    int* basep  = (int*)(ws + WS_BASE);
    int* part   = (int*)(ws + WS_PART);
    int* blkmap = (int*)(ws + WS_BLKMAP);

    hipLaunchKernelGGL(k_prepbin, dim3(1024), dim3(512), 0, stream,
                       stm, Wacc, W1, bucket, part, waccF, w1F);
    hipLaunchKernelGGL(k_scatter, dim3(BINBLK + 1), dim3(256), 0, stream,
                       bucket, part, order, cnt, basep, blkmap);

    hipFuncSetAttribute(reinterpret_cast<const void*>(k_main),
                        hipFuncAttributeMaxDynamicSharedMemorySize, LDS_BYTES);
    hipLaunchKernelGGL(k_main, dim3(MAXTILE), dim3(NT), LDS_BYTES, stream,
                       stm, nstm, Wacc, bacc, b1, W2, b2, W3, b3,
                       waccF, w1F, cnt, basep, order, blkmap, out);
}

// Round 10
// 186.109 us; speedup vs baseline: 1.3754x; 1.3754x over previous
//
#include <hip/hip_runtime.h>

typedef _Float16 f16;
typedef f16 f16x8 __attribute__((ext_vector_type(8)));
typedef float f32x4 __attribute__((ext_vector_type(4)));
typedef float f32x16 __attribute__((ext_vector_type(16)));

#define BATCH   32768
#define NF      162
#define ACCH    1024
#define KSL     192
#define NKS2    12        // 32x32x16 K-steps per 192
#define NB      8
#define DIVQ    20
#define TM      32        // rows per tile (k_main)
#define NT      256       // k_main threads (4 waves)
#define NCH     128
#define NCHUNK  (ACCH/NCH) // 8
#define MAXTILE (BATCH/TM + NB)   // 1032

#define BINBLK  256
#define RPB     (BATCH / BINBLK)  // 128 rows per binning block

// workspace layout (bytes)
#define WS_WACC16   0
#define WS_W116     (WS_WACC16 + ACCH*KSL*2)        // 393216
#define WS_BUCKET   (WS_W116 + 256*2048*2)          // 1441792
#define WS_ORDER    (WS_BUCKET + BATCH*4)           // 1572864
#define WS_CNT      (WS_ORDER + BATCH*4)            // 1703936
#define WS_BASE     (WS_CNT + 64)
#define WS_PART     (WS_BASE + 64)                  // 256*8*4 = 8192
#define WS_BLKMAP   (WS_PART + BINBLK*NB*4)         // MAXTILE ints

// k_main dynamic LDS: Xb dbuf 2*32*128*2 = 16384 + psq 128
#define LDS_BYTES   16512

// ---------------- dispatch 1: fused prep + binning ----------------
__global__ __launch_bounds__(512) void k_prepbin(const float* __restrict__ stm,
                                                 const float* __restrict__ Wacc,
                                                 const float* __restrict__ W1,
                                                 int* __restrict__ bucket,
                                                 int* __restrict__ part,
                                                 f16* __restrict__ waccF,
                                                 f16* __restrict__ w1F)
{
    if (blockIdx.x < BINBLK) {
        __shared__ int hist[NB];
        int tid = threadIdx.x;
        if (tid < NB) hist[tid] = 0;
        __syncthreads();
        int wv = tid >> 6, ln = tid & 63;
        int rowbase = blockIdx.x * RPB + wv * (RPB / 8);   // 16 rows per wave
        for (int i = 0; i < RPB / 8; i++) {
            int row = rowbase + i;
            const float* rp = stm + (long)row * NF;
            float s = 0.f;
            for (int k = ln; k < NF; k += 64) s += rp[k];
            for (int off = 32; off > 0; off >>= 1) s += __shfl_down(s, off);
            if (ln == 0) {
                int pc = (int)(s + 0.5f);
                int b = pc / DIVQ; if (b > NB - 1) b = NB - 1;
                bucket[row] = b;
                atomicAdd(&hist[b], 1);
            }
        }
        __syncthreads();
        if (tid < NB) part[blockIdx.x * NB + tid] = hist[tid];
    } else {
        int tid = (blockIdx.x - BINBLK) * blockDim.x + threadIdx.x;
        int stride = (gridDim.x - BINBLK) * blockDim.x;
        // waccF (32x32x16 B-frag): idx = (((c*12+ks)*2+kh)*128+n)*8+e, k=ks*16+kh*8+e
        for (int t = tid; t < ACCH * KSL; t += stride) {
            int e = t & 7, f = t >> 3;
            int n = f & 127, g = f >> 7;
            int kh = g & 1, h = g >> 1;
            int ks = h % NKS2, c = h / NKS2;
            int k = ks * 16 + kh * 8 + e;
            waccF[t] = (f16)((k < NF) ? Wacc[(c * 128 + n) * NF + k] : 0.f);
        }
        // w1F (16x16x32 B-frag): OUTPUT-linear, one thread per 8-elem chunk.
        // f = (((bkt*2+s)*8+c)*16 + ks*4+l4)*32 + n ; k0 = s*1024+c*128+ks*32+l4*8
        for (int f = tid; f < 256 * 2048 / 8; f += stride) {
            int n = f & 31, g = f >> 5;
            int l4b = g & 3, ks = (g >> 2) & 3, c = (g >> 4) & 7;
            int s = (g >> 7) & 1, bkt = g >> 8;
            int k0 = s * 1024 + c * 128 + ks * 32 + l4b * 8;
            const float* src = W1 + (long)(bkt * 32 + n) * 2048 + k0;
            float4 va = *(const float4*)(src);
            float4 vb = *(const float4*)(src + 4);
            f16x8 h;
            h[0]=(f16)va.x; h[1]=(f16)va.y; h[2]=(f16)va.z; h[3]=(f16)va.w;
            h[4]=(f16)vb.x; h[5]=(f16)vb.y; h[6]=(f16)vb.z; h[7]=(f16)vb.w;
            *(f16x8*)(w1F + (long)f * 8) = h;
        }
    }
}

// ---------------- dispatch 2: self-prefix scatter + setup ----------------
__global__ __launch_bounds__(256) void k_scatter(const int* __restrict__ bucket,
                                                 const int* __restrict__ part,
                                                 int* __restrict__ order,
                                                 int* __restrict__ cnt,
                                                 int* __restrict__ base,
                                                 int* __restrict__ blkmap)
{
    __shared__ int tot[NB], bas[NB], pre[NB], lcur[NB];
    __shared__ int tstart[NB + 1];
    int tid = threadIdx.x, bid = blockIdx.x;
    int w = tid >> 6, ln = tid & 63;

    if (bid < BINBLK) {
        for (int b = w; b < NB; b += 4) {
            int j0 = ln * 4;
            int p0 = part[(j0 + 0) * NB + b];
            int p1 = part[(j0 + 1) * NB + b];
            int p2 = part[(j0 + 2) * NB + b];
            int p3 = part[(j0 + 3) * NB + b];
            int s4 = p0 + p1 + p2 + p3;
            int inc = s4;
            for (int off = 1; off < 64; off <<= 1) {
                int n = __shfl_up(inc, off);
                if (ln >= off) inc += n;
            }
            if (ln == 63) tot[b] = inc;
            int excg = inc - s4;
            int g = bid >> 2;
            int prr = __shfl(excg, g);
            int q0 = __shfl(p0, g), q1 = __shfl(p1, g), q2 = __shfl(p2, g);
            int r = bid & 3;
            if (r > 0) prr += q0;
            if (r > 1) prr += q1;
            if (r > 2) prr += q2;
            if (ln == 0) pre[b] = prr;
        }
        __syncthreads();
        if (tid == 0) {
            int a = 0;
            for (int q = 0; q < NB; q++) { bas[q] = a; a += tot[q]; }
            for (int q = 0; q < NB; q++) lcur[q] = bas[q] + pre[q];
        }
        __syncthreads();
        int blkstart = bid * RPB;
        for (int i = tid; i < RPB; i += 256) {
            int row = blkstart + i;
            int b = bucket[row];
            int pos = atomicAdd(&lcur[b], 1);
            order[pos] = row;
        }
    } else {
        for (int b = w; b < NB; b += 4) {
            int j0 = ln * 4;
            int s4 = part[(j0 + 0) * NB + b] + part[(j0 + 1) * NB + b]
                   + part[(j0 + 2) * NB + b] + part[(j0 + 3) * NB + b];
            for (int off = 32; off > 0; off >>= 1) s4 += __shfl_down(s4, off);
            if (ln == 0) tot[b] = s4;
        }
        __syncthreads();
        if (tid == 0) {
            int a = 0, t = 0;
            for (int q = 0; q < NB; q++) {
                base[q] = a; cnt[q] = tot[q]; a += tot[q];
                tstart[q] = t; t += (tot[q] + TM - 1) / TM;
            }
            tstart[NB] = t;
        }
        __syncthreads();
        for (int i = tid; i < MAXTILE; i += 256) {
            int v = -1;
            for (int q = 0; q < NB; q++)
                if (i >= tstart[q] && i < tstart[q + 1]) v = q | ((i - tstart[q]) << 4);
            blkmap[i] = v;
        }
    }
}

// ---------------- dispatch 3: main fused NNUE ----------------
// __launch_bounds__ 2nd-arg law (measured R4-R9): VGPR cap = 2048/(8*arg),
// independent of block size. arg=2 -> 128 cap; body demand ~100 -> no spill.
__global__ __launch_bounds__(NT, 2) void k_main(
    const float* __restrict__ stm, const float* __restrict__ nstm,
    const float* __restrict__ Wacc, const float* __restrict__ bacc,
    const float* __restrict__ b1, const float* __restrict__ W2,
    const float* __restrict__ b2, const float* __restrict__ W3,
    const float* __restrict__ b3,
    const f16* __restrict__ waccF, const f16* __restrict__ w1F,
    const int* __restrict__ cnt, const int* __restrict__ base,
    const int* __restrict__ order, const int* __restrict__ blkmap,
    float* __restrict__ out)
{
    int bm = blkmap[blockIdx.x];
    if (bm < 0) return;
    int bkt = bm & 15, tile = bm >> 4;
    int rowbase = base[bkt] + tile * TM;
    int nrows = cnt[bkt] - tile * TM; if (nrows > TM) nrows = TM;

    extern __shared__ __align__(16) char lds_raw[];
    f16* Xb  = (f16*)lds_raw;                           // [2][32][128] dbuf swizzled
    f16* h1s = (f16*)lds_raw;                           // [32][40] alias buf0
    f16* h2s = (f16*)(lds_raw + TM * 40 * 2);           // [32][40] alias buf0
    float* psq = (float*)(lds_raw + 2 * TM * NCH * 2);  // [32]

    int tid = threadIdx.x;
    int wv = tid >> 6, ln = tid & 63;
    int l15 = ln & 15, l4 = ln >> 4, l31 = ln & 31, kh = ln >> 5;
    int mt = wv >> 1, nh = wv & 1;
    int colc = wv * 32 + l31;                 // phase1 col within chunk

    int rowclamp = (l31 < nrows) ? l31 : (nrows - 1);
    int rowidx = order[rowbase + rowclamp];

    float bb1 = b1[bkt * 32 + nh * 16 + l15];
    f32x4 h1acc; h1acc[0] = h1acc[1] = h1acc[2] = h1acc[3] = bb1;

    const float* psqw = Wacc + (long)ACCH * NF;
    const f16x8* wfr  = (const f16x8*)waccF;
    const f16x8* w1fr = (const f16x8*)w1F;

    for (int s = 0; s < 2; s++) {
        const float* rp = (s ? nstm : stm) + (long)rowidx * NF;
        // ---- A-panel (12 x f16x8 per lane) direct from global; psqt on wave 0 only ----
        f16x8 af[NKS2];
        float pp = 0.f;
        #pragma unroll
        for (int ks = 0; ks < NKS2; ks++) {
            int k0 = ks * 16 + kh * 8;
            float v0=0.f,v1=0.f,v2=0.f,v3=0.f,v4=0.f,v5=0.f,v6=0.f,v7=0.f;
            if (k0 <= 152) {
                float2 a0 = *(const float2*)(rp + k0);
                float2 a1 = *(const float2*)(rp + k0 + 2);
                float2 a2 = *(const float2*)(rp + k0 + 4);
                float2 a3 = *(const float2*)(rp + k0 + 6);
                v0=a0.x; v1=a0.y; v2=a1.x; v3=a1.y;
                v4=a2.x; v5=a2.y; v6=a3.x; v7=a3.y;
                if (wv == 0) {
                    float4 pa = *(const float4*)(psqw + k0);
                    float4 pb = *(const float4*)(psqw + k0 + 4);
                    pp += v0*pa.x + v1*pa.y + v2*pa.z + v3*pa.w
                        + v4*pb.x + v5*pb.y + v6*pb.z + v7*pb.w;
                }
            } else if (k0 == 160) {
                float2 a0 = *(const float2*)(rp + 160);
                v0 = a0.x; v1 = a0.y;
                if (wv == 0) pp += v0*psqw[160] + v1*psqw[161];
            }
            f16x8 h;
            h[0]=(f16)v0; h[1]=(f16)v1; h[2]=(f16)v2; h[3]=(f16)v3;
            h[4]=(f16)v4; h[5]=(f16)v5; h[6]=(f16)v6; h[7]=(f16)v7;
            af[ks] = h;
        }
        if (wv == 0) {
            pp += __shfl_xor(pp, 32);
            if (kh == 0) {
                if (s) psq[l31] -= 0.5f * pp;
                else   psq[l31]  = 0.5f * pp;
            }
        }

        for (int c = 0; c < NCHUNK; c++) {
            // ---- phase 1: 32x32x16, A regs, B global (L2-hot) ----
            float bias = bacc[c * NCH + colc];
            f32x16 acc;
            #pragma unroll
            for (int q = 0; q < 16; q++) acc[q] = bias;
            const f16x8* wp = wfr + ((c * NKS2) * 2 + kh) * 128 + colc;
            #pragma unroll
            for (int ks = 0; ks < NKS2; ks++) {
                f16x8 bf = wp[ks * 256];
                acc = __builtin_amdgcn_mfma_f32_32x32x16_f16(af[ks], bf, acc, 0, 0, 0);
            }
            // epilogue: clip^2 -> Xb[(s*8+c)&1] (dbuf: 1 barrier per chunk)
            f16* xb = Xb + (((s << 3) | c) & 1) * TM * NCH;
            #pragma unroll
            for (int reg = 0; reg < 16; reg++) {
                int rr = 4 * kh + (reg & 3) + 8 * (reg >> 2);
                float v = acc[reg];
                v = fminf(fmaxf(v, 0.f), 1.f);
                v = v * v;
                xb[rr * NCH + ((((colc >> 3) ^ (rr & 7)) << 3) | (colc & 7))] = (f16)v;
            }
            __syncthreads();
            // ---- phase 2: h1 += act @ W1_chunk^T (16x16x32) ----
            const f16x8* w1p = w1fr + ((bkt * 2 + s) * 8 + c) * 512;
            #pragma unroll
            for (int ks = 0; ks < NCH / 32; ks++) {
                int s0 = ks * 4 + l4;
                int row = mt * 16 + l15;
                f16x8 a = *(const f16x8*)(xb + row * NCH + ((s0 ^ (row & 7)) << 3));
                f16x8 b = w1p[s0 * 32 + nh * 16 + l15];
                h1acc = __builtin_amdgcn_mfma_f32_16x16x32_f16(a, b, h1acc, 0, 0, 0);
            }
        }
    }
    __syncthreads();   // all phase2 reads done before h1s/h2s overwrite buf0

    // ---- h1 finalize ----
    #pragma unroll
    for (int jr = 0; jr < 4; jr++) {
        int row = mt * 16 + l4 * 4 + jr;
        int col = nh * 16 + l15;
        float v = fminf(fmaxf(h1acc[jr], 0.f), 1.f);
        h1s[row * 40 + col] = (f16)v;
    }
    __syncthreads();

    // ---- layer 3 ----
    {
        int nn = nh * 16 + l15;
        const float* w2r = W2 + (bkt * 32 + nn) * 32;
        float4 wa = *(const float4*)(w2r + l4 * 8);
        float4 wb = *(const float4*)(w2r + l4 * 8 + 4);
        f16x8 bfr;
        bfr[0]=(f16)wa.x; bfr[1]=(f16)wa.y; bfr[2]=(f16)wa.z; bfr[3]=(f16)wa.w;
        bfr[4]=(f16)wb.x; bfr[5]=(f16)wb.y; bfr[6]=(f16)wb.z; bfr[7]=(f16)wb.w;
        int row = mt * 16 + l15;
        f16x8 a = *(const f16x8*)(h1s + row * 40 + l4 * 8);
        float bb2 = b2[bkt * 32 + nn];
        f32x4 acc2; acc2[0] = acc2[1] = acc2[2] = acc2[3] = bb2;
        acc2 = __builtin_amdgcn_mfma_f32_16x16x32_f16(a, bfr, acc2, 0, 0, 0);
        #pragma unroll
        for (int jr = 0; jr < 4; jr++) {
            int r2 = mt * 16 + l4 * 4 + jr;
            float v = fminf(fmaxf(acc2[jr], 0.f), 1.f);
            h2s[r2 * 40 + nn] = (f16)v;
        }
    }
    __syncthreads();

    // ---- layer 4 + psqt ----
    if (tid < nrows) {
        const float* w3r = W3 + bkt * 32;
        float o = b3[bkt] + psq[tid];
        #pragma unroll 8
        for (int n = 0; n < 32; n++) o += (float)h2s[tid * 40 + n] * w3r[n];
        out[order[rowbase + tid]] = o;
    }
}

// ---------------- launcher ----------------
extern "C" void kernel_launch(void* const* d_in, const int* in_sizes, int n_in,
                              void* d_out, int out_size, void* d_ws, size_t ws_size,
                              hipStream_t stream)
{
    (void)in_sizes; (void)n_in; (void)out_size; (void)ws_size;
    const float* stm  = (const float*)d_in[0];
    const float* nstm = (const float*)d_in[1];
    const float* Wacc = (const float*)d_in[2];
    const float* bacc = (const float*)d_in[3];
    const float* W1   = (const float*)d_in[4];
    const float* b1   = (const float*)d_in[5];
    const float* W2   = (const float*)d_in[6];
    const float* b2   = (const float*)d_in[7];
    const float* W3   = (const float*)d_in[8];
    const float* b3   = (const float*)d_in[9];
    float* out = (float*)d_out;

    char* ws = (char*)d_ws;
    f16* waccF  = (f16*)(ws + WS_WACC16);
    f16* w1F    = (f16*)(ws + WS_W116);
    int* bucket = (int*)(ws + WS_BUCKET);
    int* order  = (int*)(ws + WS_ORDER);
    int* cnt    = (int*)(ws + WS_CNT);
    int* basep  = (int*)(ws + WS_BASE);
    int* part   = (int*)(ws + WS_PART);
    int* blkmap = (int*)(ws + WS_BLKMAP);

    hipLaunchKernelGGL(k_prepbin, dim3(1024), dim3(512), 0, stream,
                       stm, Wacc, W1, bucket, part, waccF, w1F);
    hipLaunchKernelGGL(k_scatter, dim3(BINBLK + 1), dim3(256), 0, stream,
                       bucket, part, order, cnt, basep, blkmap);

    hipFuncSetAttribute(reinterpret_cast<const void*>(k_main),
                        hipFuncAttributeMaxDynamicSharedMemorySize, LDS_BYTES);
    hipLaunchKernelGGL(k_main, dim3(MAXTILE), dim3(NT), LDS_BYTES, stream,
                       stm, nstm, Wacc, bacc, b1, W2, b2, W3, b3,
                       waccF, w1F, cnt, basep, order, blkmap, out);
}